// Round 6
// baseline (1150.730 us; speedup 1.0000x reference)
//
#include <hip/hip_runtime.h>
#include <cstdint>
#include <cstddef>

typedef __bf16 bf16_t;
typedef bf16_t bf16x8 __attribute__((ext_vector_type(8)));
typedef float floatx4 __attribute__((ext_vector_type(4)));
typedef unsigned long long u64;

#define B_   128
#define T_   64
#define H_   512
#define IN_  2048
#define FS_  1536
#define M_   (B_ * T_)   // 8192
#define GB_  64
#define SENT (~0ull)     // 0xFF... = 4x bf16 NaN — GRU outputs can never be NaN

// ---------------------------------------------------------------------------
__device__ __forceinline__ void async16(void* lds, const void* gp) {
  __builtin_amdgcn_global_load_lds(
      (const __attribute__((address_space(1))) void*)gp,
      (__attribute__((address_space(3))) void*)lds, 16, 0, 0);
}

// Coherent (agent-scope relaxed) ops — served at the MALL coherence point.
__device__ __forceinline__ u64 cload64(const u64* p) {
  return __hip_atomic_load((u64*)p, __ATOMIC_RELAXED, __HIP_MEMORY_SCOPE_AGENT);
}
__device__ __forceinline__ void cstore64(u64* p, u64 v) {
  __hip_atomic_store(p, v, __ATOMIC_RELAXED, __HIP_MEMORY_SCOPE_AGENT);
}

__device__ __forceinline__ float fsigmoid(float x) {
  return __builtin_amdgcn_rcpf(1.f + __expf(-x));
}
__device__ __forceinline__ float ftanh(float x) {
  return 2.f * __builtin_amdgcn_rcpf(1.f + __expf(-2.f * x)) - 1.f;
}

// ---------------------------------------------------------------------------
// Fused fp32->bf16 convert for all four tensors in ONE launch.
// ---------------------------------------------------------------------------
__global__ __launch_bounds__(256) void cvt_all_k(
    const float* __restrict__ s0, bf16_t* __restrict__ d0, int e0,
    const float* __restrict__ s1, bf16_t* __restrict__ d1, int e1,
    const float* __restrict__ s2, bf16_t* __restrict__ d2, int e2,
    const float* __restrict__ s3, bf16_t* __restrict__ d3, int e3) {
  int i = blockIdx.x * 256 + threadIdx.x;
  if (i >= e3) return;
  const float* s; bf16_t* d; int base;
  if (i < e1) {
    if (i < e0) { s = s0; d = d0; base = 0;  }
    else        { s = s1; d = d1; base = e0; }
  } else {
    if (i < e2) { s = s2; d = d2; base = e1; }
    else        { s = s3; d = d3; base = e2; }
  }
  size_t j = (size_t)(i - base);
  const float4* s4 = (const float4*)s;
  float4 v0 = s4[2 * j];
  float4 v1 = s4[2 * j + 1];
  bf16x8 o;
  o[0] = (bf16_t)v0.x; o[1] = (bf16_t)v0.y; o[2] = (bf16_t)v0.z; o[3] = (bf16_t)v0.w;
  o[4] = (bf16_t)v1.x; o[5] = (bf16_t)v1.y; o[6] = (bf16_t)v1.z; o[7] = (bf16_t)v1.w;
  *(bf16x8*)(d + j * 8) = o;
}

// ---------------------------------------------------------------------------
// DUAL GEMM, 256x256 tile, BK=32, 8 waves (512 threads), 2-phase counted-vmcnt.
// Rationale: the GEMM is L2/L3-BANDWIDTH bound on operand re-fetch. 256^2
// tiles halve per-FLOP operand traffic vs 128^2 (GEMM1: 768MB->384MB).
// Grid 320 blocks, LDS 64KB -> 2 blocks/CU, all blocks co-resident (no tail).
// Staging identity preserved: lane offset (l>>2)*32+(l&3)*8 == l*8 elems ==
// lane*16B, so global_load_lds's uniform-base+lane*16 dest layout is exact.
// Pipeline (verified round 5, unchanged): stage t0,t1; per iter
// vmcnt(4)[own tile landed, next in flight] -> s_barrier -> ds_read+MFMA ->
// s_barrier -> restage for t+2. Last iter vmcnt(0).
// ---------------------------------------------------------------------------
#define BM 256
#define BN 256
#define BK 32

__global__ __launch_bounds__(512, 4) void gemm_dual(
    const bf16_t* __restrict__ A1g, const bf16_t* __restrict__ W1g,
    const float* __restrict__ bias1, float* __restrict__ C1g,
    const bf16_t* __restrict__ A2g, const bf16_t* __restrict__ W2g,
    const float* __restrict__ bias2, float* __restrict__ C2g) {
  __shared__ __align__(16) bf16_t As[2][BM * BK];   // 2 x 16 KB
  __shared__ __align__(16) bf16_t Bs[2][BN * BK];   // 2 x 16 KB

  const int tid  = threadIdx.x;
  const int lane = tid & 63;
  const int wave = tid >> 6;          // 0..7
  const int wr = wave >> 1;           // 0..3  (row quadrant, 64 rows each)
  const int wc = wave & 1;            // 0..1  (col half, 128 cols each)

  // ---- sub-kernel select + per-range XCD swizzle (block-uniform) ----
  const bf16_t *A, *Bm; const float* bias; float* C;
  int N, K, id, gx;
  const int p = blockIdx.x;
  if (p < 192) {
    A = A1g; Bm = W1g; bias = bias1; C = C1g;
    N = 3 * H_; K = IN_;
    id = (p & 7) * 24 + (p >> 3);   // nwg=192, chunk=24
    gx = 6;                         // 1536/256
  } else {
    const int q = p - 192;
    A = A2g; Bm = W2g; bias = bias2; C = C2g;
    N = 2 * H_; K = FS_;
    id = (q & 7) * 16 + (q >> 3);   // nwg=128, chunk=16
    gx = 4;                         // 1024/256
  }
  const int bx = id % gx;
  const int by = id / gx;
  const int mblk = by * BM;
  const int nblk = bx * BN;

  const int sr = lane >> 2;           // 0..15
  const int sc = (lane & 3) * 8;      // 0,8,16,24
  const int so = wave * 1024;         // wave's 32-row chunk in LDS (elems)

  const bf16_t* Ag0 = A + (size_t)(mblk + wave * 32 + sr) * K + sc;
  const bf16_t* Ag1 = A + (size_t)(mblk + wave * 32 + 16 + sr) * K + sc;
  const bf16_t* Bg0 = Bm + (size_t)(nblk + wave * 32 + sr) * K + sc;
  const bf16_t* Bg1 = Bm + (size_t)(nblk + wave * 32 + 16 + sr) * K + sc;

  floatx4 acc[4][8] = {};

  const int fm = lane & 15;
  const int fk = (lane >> 4) * 8;

  auto stage = [&](int buf, int kt) {
    async16(As[buf] + so,       Ag0 + kt);
    async16(As[buf] + so + 512, Ag1 + kt);
    async16(Bs[buf] + so,       Bg0 + kt);
    async16(Bs[buf] + so + 512, Bg1 + kt);
  };

  // ---- prologue: 2 tiles in flight (K >= 2*BK for both sub-GEMMs) ----
  stage(0, 0);
  stage(1, BK);

  int cur = 0;
  for (int kt = 0; kt < K; kt += BK) {
    // wait for MY current-tile loads only; keep next tile's loads in flight
    if (kt + BK < K)
      asm volatile("s_waitcnt vmcnt(4)" ::: "memory");
    else
      asm volatile("s_waitcnt vmcnt(0)" ::: "memory");
    asm volatile("s_barrier" ::: "memory");   // all waves' tile-kt writes landed

    bf16x8 a[4], b[8];
#pragma unroll
    for (int i = 0; i < 4; i++)
      a[i] = *(const bf16x8*)(As[cur] + (wr * 64 + i * 16 + fm) * BK + fk);
#pragma unroll
    for (int j = 0; j < 8; j++)
      b[j] = *(const bf16x8*)(Bs[cur] + (wc * 128 + j * 16 + fm) * BK + fk);
#pragma unroll
    for (int i = 0; i < 4; i++)
#pragma unroll
      for (int j = 0; j < 8; j++)
        acc[i][j] = __builtin_amdgcn_mfma_f32_16x16x32_bf16(a[i], b[j], acc[i][j], 0, 0, 0);

    asm volatile("s_barrier" ::: "memory");   // all waves done reading buf[cur]
    if (kt + 2 * BK < K) stage(cur, kt + 2 * BK);   // refill for tile kt+2
    cur ^= 1;
  }

  const int en  = nblk + wc * 128 + fm;
  const int em0 = mblk + wr * 64 + (lane >> 4) * 4;
#pragma unroll
  for (int j = 0; j < 8; j++) {
    int col = en + j * 16;
    float bv = bias[col];
#pragma unroll
    for (int i = 0; i < 4; i++) {
#pragma unroll
      for (int r = 0; r < 4; r++) {
        int row = em0 + i * 16 + r;
        C[(size_t)row * N + col] = acc[i][j][r] + bv;
      }
    }
  }
}

// ---------------------------------------------------------------------------
// Persistent GRU scan — FLAGLESS producer/consumer.
// BYTE-IDENTICAL to the round-2..5 PASSING version. The poll/publish
// protocol is not modified until the round-1 timing-dependent failure is
// explained.
// ---------------------------------------------------------------------------
__global__ __launch_bounds__(256, 1) void gru_scan(
    const float* __restrict__ Whh_f,  // [3H][H] fp32
    const float* __restrict__ bhh,
    const float* __restrict__ gi,     // [M][3H]
    const float* __restrict__ gf,     // [M][2H]
    bf16_t* __restrict__ hbuf,        // 64 x 65536 elems (8 MB), 0xFF-init
    float* __restrict__ out) {        // eo [B*T][H] ++ hT [B][H]
  __shared__ __align__(16) bf16_t wlds[48 * 64 * 8];  // 48 KB (init staging only)
  __shared__ __align__(16) bf16_t swp[4][256];        // repack scratch

  const int tid  = threadIdx.x;
  const int lane = tid & 63;
  const int w    = tid >> 6;
  const int lm   = lane & 15;
  const int lq   = lane >> 4;
  const int c    = blockIdx.x >> 1;
  const int mh   = blockIdx.x & 1;
  const int n0   = c * 16;

  // ---- W_hh slice -> LDS (fragment order), once ----
  for (int f = w; f < 48; f += 4) {
    int g = f >> 4, kt = f & 15;
    const float* src = Whh_f + (size_t)(g * H_ + n0 + lm) * H_ + kt * 32 + lq * 8;
    float4 v0 = *(const float4*)src;
    float4 v1 = *(const float4*)(src + 4);
    bf16x8 o;
    o[0] = (bf16_t)v0.x; o[1] = (bf16_t)v0.y; o[2] = (bf16_t)v0.z; o[3] = (bf16_t)v0.w;
    o[4] = (bf16_t)v1.x; o[5] = (bf16_t)v1.y; o[6] = (bf16_t)v1.z; o[7] = (bf16_t)v1.w;
    *(bf16x8*)(wlds + (f * 64 + lane) * 8) = o;
  }

  // ---- publish zeros into step-0 buffer (zeros != sentinel) ----
  {
    u64* z = (u64*)(hbuf + (((size_t)mh * 32 + c) * 64 + w * 16) * 16) + lane;
    cstore64(z, 0ull);
  }
  __syncthreads();   // wlds ready

  // ---- hoist W_hh fragments into registers (loop-invariant over t) ----
  bf16x8 wb[3][16];
#pragma unroll
  for (int g = 0; g < 3; ++g)
#pragma unroll
    for (int kt = 0; kt < 16; ++kt)
      wb[g][kt] = *(const bf16x8*)(wlds + ((g * 16 + kt) * 64 + lane) * 8);

  const float b0 = bhh[n0 + lm];
  const float b1 = bhh[H_ + n0 + lm];
  const float b2 = bhh[2 * H_ + n0 + lm];

  const int m0 = mh * 64 + w * 16;
  float hp[4] = {0.f, 0.f, 0.f, 0.f};

  float pir[4], pii[4], pin[4], pfr[4], pfi[4];
  auto prefetch = [&](int t) {
#pragma unroll
    for (int r = 0; r < 4; ++r) {
      size_t mrow = (size_t)(m0 + lq * 4 + r) * T_ + t;
      const float* gip = gi + mrow * (3 * H_) + n0 + lm;
      pir[r] = gip[0];
      pii[r] = gip[H_];
      pin[r] = gip[2 * H_];
      const float* gfp = gf + mrow * (2 * H_) + n0 + lm;
      pfr[r] = gfp[0];
      pfi[r] = gfp[H_];
    }
  };
  prefetch(0);

  // a-frag addressing within a step buffer:
  //   elem = mh*32768 + ct*1024 + (w*16+lm)*16 + colin, ct = kt*2+(lq>>1),
  //   colin = (lq&1)*8
  const size_t habase = (size_t)mh * 32768 + ((size_t)w * 16 + lm) * 16 +
                        (size_t)(lq >> 1) * 1024 + (lq & 1) * 8;

  for (int t = 0; t < T_; ++t) {
    const bf16_t* hstep = hbuf + (size_t)t * 65536;
    union { u64 u[2]; bf16x8 v; } a[16];
    // ---- poll the data itself until no lane sees the NaN sentinel ----
    for (;;) {
      int ok = 1;
#pragma unroll
      for (int kt = 0; kt < 16; ++kt) {
        const u64* ap = (const u64*)(hstep + habase + (size_t)kt * 2048);
        a[kt].u[0] = cload64(ap);
        a[kt].u[1] = cload64(ap + 1);
      }
#pragma unroll
      for (int kt = 0; kt < 16; ++kt)
        ok &= (a[kt].u[0] != SENT) & (a[kt].u[1] != SENT);
      if (__all(ok)) break;
      __builtin_amdgcn_s_sleep(1);
    }

    // ---- MFMA: W in registers, two 8-deep chains per gate ----
    floatx4 acc0[3] = {}, acc1[3] = {};
#pragma unroll
    for (int g = 0; g < 3; ++g)
#pragma unroll
      for (int kt = 0; kt < 16; kt += 2) {
        acc0[g] = __builtin_amdgcn_mfma_f32_16x16x32_bf16(a[kt].v,     wb[g][kt],     acc0[g], 0, 0, 0);
        acc1[g] = __builtin_amdgcn_mfma_f32_16x16x32_bf16(a[kt + 1].v, wb[g][kt + 1], acc1[g], 0, 0, 0);
      }

    // ---- elementwise (no stores yet) ----
    float hy[4];
#pragma unroll
    for (int r = 0; r < 4; ++r) {
      float rg = fsigmoid(pir[r] + acc0[0][r] + acc1[0][r] + b0 + pfr[r]);
      float ig = fsigmoid(pii[r] + acc0[1][r] + acc1[1][r] + b1 + pfi[r]);
      float ng = ftanh(pin[r] + rg * (acc0[2][r] + acc1[2][r] + b2));
      hy[r] = ng + ig * (hp[r] - ng);
      hp[r] = hy[r];
      swp[w][(lq * 4 + r) * 16 + lm] = (bf16_t)hy[r];
    }

    // ---- publish ASAP: wave-internal LDS repack -> one 8B store per lane ----
    if (t + 1 < T_) {
      asm volatile("s_waitcnt lgkmcnt(0)" ::: "memory");
      u64 pk = *(const u64*)(&swp[w][0] + lane * 4);
      u64* dst = (u64*)(hbuf + (size_t)(t + 1) * 65536 +
                        (((size_t)mh * 32 + c) * 64 + w * 16) * 16) + lane;
      cstore64(dst, pk);   // no drain, no flag — consumers poll the data
    }

    // ---- off-critical-path: eo stores, hT, next prefetch ----
#pragma unroll
    for (int r = 0; r < 4; ++r) {
      int brow = m0 + lq * 4 + r;
      size_t mrow = (size_t)brow * T_ + t;
      out[mrow * H_ + n0 + lm] = hy[r];
      if (t == T_ - 1)
        out[(size_t)M_ * H_ + (size_t)brow * H_ + n0 + lm] = hy[r];
    }
    if (t + 1 < T_) prefetch(t + 1);
  }
}

// ---------------------------------------------------------------------------
extern "C" void kernel_launch(void* const* d_in, const int* in_sizes, int n_in,
                              void* d_out, int out_size, void* d_ws, size_t ws_size,
                              hipStream_t stream) {
  const float* feat0 = (const float*)d_in[0];
  const float* feat1 = (const float*)d_in[1];
  const float* W_ih  = (const float*)d_in[2];
  const float* b_ih  = (const float*)d_in[3];
  const float* W_hh  = (const float*)d_in[4];
  const float* b_hh  = (const float*)d_in[5];
  const float* W_fh  = (const float*)d_in[6];
  const float* b_fh  = (const float*)d_in[7];
  float* out = (float*)d_out;

  char* p = (char*)d_ws;
  float*  gi   = (float*)p;  p += (size_t)M_ * 3 * H_ * 4;   // 48 MB
  float*  gf   = (float*)p;  p += (size_t)M_ * 2 * H_ * 4;   // 32 MB
  bf16_t* A1   = (bf16_t*)p; p += (size_t)M_ * IN_ * 2;      // 32 MB
  bf16_t* A0   = (bf16_t*)p; p += (size_t)M_ * FS_ * 2;      // 24 MB
  bf16_t* Wihb = (bf16_t*)p; p += (size_t)3 * H_ * IN_ * 2;  // 6 MB
  bf16_t* Wfhb = (bf16_t*)p; p += (size_t)2 * H_ * FS_ * 2;  // 3 MB

  // h step-buffers alias A0 (dual-GEMM has finished reading A0 by then)
  bf16_t* hbuf = A0;   // 64 steps x 128 KB = 8 MB < 24 MB

  // ---- single fused convert launch (4 regions) ----
  const int e0 = (int)((size_t)M_ * IN_ / 8);                    // feat1 -> A1
  const int e1 = e0 + (int)((size_t)M_ * FS_ / 8);               // feat0 -> A0
  const int e2 = e1 + (int)((size_t)3 * H_ * IN_ / 8);           // W_ih  -> Wihb
  const int e3 = e2 + (int)((size_t)2 * H_ * FS_ / 8);           // W_fh  -> Wfhb
  cvt_all_k<<<(e3 + 255) / 256, 256, 0, stream>>>(
      feat1, A1, e0, feat0, A0, e1, W_ih, Wihb, e2, W_fh, Wfhb, e3);

  // ---- both GEMMs in one launch: 192 + 128 = 320 blocks of 512 threads ----
  gemm_dual<<<320, 512, 0, stream>>>(
      A1, Wihb, b_ih, gi,
      A0, Wfhb, b_fh, gf);

  // sentinel-fill the h step-buffers (after dual-GEMM consumed A0)
  hipMemsetAsync(hbuf, 0xFF, (size_t)T_ * 65536 * sizeof(bf16_t), stream);

  gru_scan<<<GB_, 256, 0, stream>>>(W_hh, b_hh, gi, gf, hbuf, out);
}

// Round 7
// 493.004 us; speedup vs baseline: 2.3341x; 2.3341x over previous
//
#include <hip/hip_runtime.h>
#include <cstdint>
#include <cstddef>

typedef __bf16 bf16_t;
typedef bf16_t bf16x8 __attribute__((ext_vector_type(8)));
typedef float floatx4 __attribute__((ext_vector_type(4)));
typedef unsigned long long u64;

#define B_   128
#define T_   64
#define H_   512
#define IN_  2048
#define FS_  1536
#define M_   (B_ * T_)   // 8192
#define GB_  64
#define SENT (~0ull)     // 0xFF... = 4x bf16 NaN — GRU outputs can never be NaN

// ---------------------------------------------------------------------------
__device__ __forceinline__ void async16(void* lds, const void* gp) {
  __builtin_amdgcn_global_load_lds(
      (const __attribute__((address_space(1))) void*)gp,
      (__attribute__((address_space(3))) void*)lds, 16, 0, 0);
}

// Coherent (agent-scope relaxed) ops — served at the MALL coherence point.
__device__ __forceinline__ u64 cload64(const u64* p) {
  return __hip_atomic_load((u64*)p, __ATOMIC_RELAXED, __HIP_MEMORY_SCOPE_AGENT);
}
__device__ __forceinline__ void cstore64(u64* p, u64 v) {
  __hip_atomic_store(p, v, __ATOMIC_RELAXED, __HIP_MEMORY_SCOPE_AGENT);
}

__device__ __forceinline__ float fsigmoid(float x) {
  return __builtin_amdgcn_rcpf(1.f + __expf(-x));
}
__device__ __forceinline__ float ftanh(float x) {
  return 2.f * __builtin_amdgcn_rcpf(1.f + __expf(-2.f * x)) - 1.f;
}

// ---------------------------------------------------------------------------
// Fused fp32->bf16 convert for all four tensors in ONE launch.
// ---------------------------------------------------------------------------
__global__ __launch_bounds__(256) void cvt_all_k(
    const float* __restrict__ s0, bf16_t* __restrict__ d0, int e0,
    const float* __restrict__ s1, bf16_t* __restrict__ d1, int e1,
    const float* __restrict__ s2, bf16_t* __restrict__ d2, int e2,
    const float* __restrict__ s3, bf16_t* __restrict__ d3, int e3) {
  int i = blockIdx.x * 256 + threadIdx.x;
  if (i >= e3) return;
  const float* s; bf16_t* d; int base;
  if (i < e1) {
    if (i < e0) { s = s0; d = d0; base = 0;  }
    else        { s = s1; d = d1; base = e0; }
  } else {
    if (i < e2) { s = s2; d = d2; base = e1; }
    else        { s = s3; d = d3; base = e2; }
  }
  size_t j = (size_t)(i - base);
  const float4* s4 = (const float4*)s;
  float4 v0 = s4[2 * j];
  float4 v1 = s4[2 * j + 1];
  bf16x8 o;
  o[0] = (bf16_t)v0.x; o[1] = (bf16_t)v0.y; o[2] = (bf16_t)v0.z; o[3] = (bf16_t)v0.w;
  o[4] = (bf16_t)v1.x; o[5] = (bf16_t)v1.y; o[6] = (bf16_t)v1.z; o[7] = (bf16_t)v1.w;
  *(bf16x8*)(d + j * 8) = o;
}

// ---------------------------------------------------------------------------
// DUAL GEMM, 256x256 tile, BK=32, 8 waves (512 threads), 2-phase counted-vmcnt.
//
// ROUND-7 FIX: round 6's __launch_bounds__(512, 4) was interpreted as a
// 4-BLOCK/CU occupancy floor (8 waves/SIMD -> 64-VGPR cap) and spilled the
// entire acc[4][8] to scratch (VGPR_Count=64, WRITE_SIZE=1.9GB, 789 us).
// Min-occupancy arg REMOVED: allocator takes ~190 VGPRs -> 2 waves/SIMD,
// 1 block/CU. Everything else is byte-identical to the (correct-but-spilled,
// absmax-verified) round-6 kernel.
//
// Rationale unchanged: 256^2 tiles halve L2/L3 operand re-fetch vs 128^2
// (GEMM1 768->384 MB, GEMM2 384->192 MB). Staging identity: lane offset
// (l>>2)*32+(l&3)*8 == l*8 elems == lane*16B, matching global_load_lds's
// uniform-base+lane*16 destination.
// Pipeline (verified rounds 5/6): stage t0,t1; per iter vmcnt(4) [own tile
// landed, next in flight] -> s_barrier -> ds_read+MFMA -> s_barrier ->
// restage for t+2. Last iter vmcnt(0).
// ---------------------------------------------------------------------------
#define BM 256
#define BN 256
#define BK 32

__global__ __launch_bounds__(512) void gemm_dual(
    const bf16_t* __restrict__ A1g, const bf16_t* __restrict__ W1g,
    const float* __restrict__ bias1, float* __restrict__ C1g,
    const bf16_t* __restrict__ A2g, const bf16_t* __restrict__ W2g,
    const float* __restrict__ bias2, float* __restrict__ C2g) {
  __shared__ __align__(16) bf16_t As[2][BM * BK];   // 2 x 16 KB
  __shared__ __align__(16) bf16_t Bs[2][BN * BK];   // 2 x 16 KB

  const int tid  = threadIdx.x;
  const int lane = tid & 63;
  const int wave = tid >> 6;          // 0..7
  const int wr = wave >> 1;           // 0..3  (row quadrant, 64 rows each)
  const int wc = wave & 1;            // 0..1  (col half, 128 cols each)

  // ---- sub-kernel select + per-range XCD swizzle (block-uniform) ----
  const bf16_t *A, *Bm; const float* bias; float* C;
  int N, K, id, gx;
  const int p = blockIdx.x;
  if (p < 192) {
    A = A1g; Bm = W1g; bias = bias1; C = C1g;
    N = 3 * H_; K = IN_;
    id = (p & 7) * 24 + (p >> 3);   // nwg=192, chunk=24
    gx = 6;                         // 1536/256
  } else {
    const int q = p - 192;
    A = A2g; Bm = W2g; bias = bias2; C = C2g;
    N = 2 * H_; K = FS_;
    id = (q & 7) * 16 + (q >> 3);   // nwg=128, chunk=16
    gx = 4;                         // 1024/256
  }
  const int bx = id % gx;
  const int by = id / gx;
  const int mblk = by * BM;
  const int nblk = bx * BN;

  const int sr = lane >> 2;           // 0..15
  const int sc = (lane & 3) * 8;      // 0,8,16,24
  const int so = wave * 1024;         // wave's 32-row chunk in LDS (elems)

  const bf16_t* Ag0 = A + (size_t)(mblk + wave * 32 + sr) * K + sc;
  const bf16_t* Ag1 = A + (size_t)(mblk + wave * 32 + 16 + sr) * K + sc;
  const bf16_t* Bg0 = Bm + (size_t)(nblk + wave * 32 + sr) * K + sc;
  const bf16_t* Bg1 = Bm + (size_t)(nblk + wave * 32 + 16 + sr) * K + sc;

  floatx4 acc[4][8] = {};

  const int fm = lane & 15;
  const int fk = (lane >> 4) * 8;

  auto stage = [&](int buf, int kt) {
    async16(As[buf] + so,       Ag0 + kt);
    async16(As[buf] + so + 512, Ag1 + kt);
    async16(Bs[buf] + so,       Bg0 + kt);
    async16(Bs[buf] + so + 512, Bg1 + kt);
  };

  // ---- prologue: 2 tiles in flight (K >= 2*BK for both sub-GEMMs) ----
  stage(0, 0);
  stage(1, BK);

  int cur = 0;
  for (int kt = 0; kt < K; kt += BK) {
    // wait for MY current-tile loads only; keep next tile's loads in flight
    if (kt + BK < K)
      asm volatile("s_waitcnt vmcnt(4)" ::: "memory");
    else
      asm volatile("s_waitcnt vmcnt(0)" ::: "memory");
    asm volatile("s_barrier" ::: "memory");   // all waves' tile-kt writes landed

    bf16x8 a[4], b[8];
#pragma unroll
    for (int i = 0; i < 4; i++)
      a[i] = *(const bf16x8*)(As[cur] + (wr * 64 + i * 16 + fm) * BK + fk);
#pragma unroll
    for (int j = 0; j < 8; j++)
      b[j] = *(const bf16x8*)(Bs[cur] + (wc * 128 + j * 16 + fm) * BK + fk);
#pragma unroll
    for (int i = 0; i < 4; i++)
#pragma unroll
      for (int j = 0; j < 8; j++)
        acc[i][j] = __builtin_amdgcn_mfma_f32_16x16x32_bf16(a[i], b[j], acc[i][j], 0, 0, 0);

    asm volatile("s_barrier" ::: "memory");   // all waves done reading buf[cur]
    if (kt + 2 * BK < K) stage(cur, kt + 2 * BK);   // refill for tile kt+2
    cur ^= 1;
  }

  const int en  = nblk + wc * 128 + fm;
  const int em0 = mblk + wr * 64 + (lane >> 4) * 4;
#pragma unroll
  for (int j = 0; j < 8; j++) {
    int col = en + j * 16;
    float bv = bias[col];
#pragma unroll
    for (int i = 0; i < 4; i++) {
#pragma unroll
      for (int r = 0; r < 4; r++) {
        int row = em0 + i * 16 + r;
        C[(size_t)row * N + col] = acc[i][j][r] + bv;
      }
    }
  }
}

// ---------------------------------------------------------------------------
// Persistent GRU scan — FLAGLESS producer/consumer.
// BYTE-IDENTICAL to the round-2..6 PASSING version. The poll/publish
// protocol is not modified until the round-1 timing-dependent failure is
// explained.
// ---------------------------------------------------------------------------
__global__ __launch_bounds__(256, 1) void gru_scan(
    const float* __restrict__ Whh_f,  // [3H][H] fp32
    const float* __restrict__ bhh,
    const float* __restrict__ gi,     // [M][3H]
    const float* __restrict__ gf,     // [M][2H]
    bf16_t* __restrict__ hbuf,        // 64 x 65536 elems (8 MB), 0xFF-init
    float* __restrict__ out) {        // eo [B*T][H] ++ hT [B][H]
  __shared__ __align__(16) bf16_t wlds[48 * 64 * 8];  // 48 KB (init staging only)
  __shared__ __align__(16) bf16_t swp[4][256];        // repack scratch

  const int tid  = threadIdx.x;
  const int lane = tid & 63;
  const int w    = tid >> 6;
  const int lm   = lane & 15;
  const int lq   = lane >> 4;
  const int c    = blockIdx.x >> 1;
  const int mh   = blockIdx.x & 1;
  const int n0   = c * 16;

  // ---- W_hh slice -> LDS (fragment order), once ----
  for (int f = w; f < 48; f += 4) {
    int g = f >> 4, kt = f & 15;
    const float* src = Whh_f + (size_t)(g * H_ + n0 + lm) * H_ + kt * 32 + lq * 8;
    float4 v0 = *(const float4*)src;
    float4 v1 = *(const float4*)(src + 4);
    bf16x8 o;
    o[0] = (bf16_t)v0.x; o[1] = (bf16_t)v0.y; o[2] = (bf16_t)v0.z; o[3] = (bf16_t)v0.w;
    o[4] = (bf16_t)v1.x; o[5] = (bf16_t)v1.y; o[6] = (bf16_t)v1.z; o[7] = (bf16_t)v1.w;
    *(bf16x8*)(wlds + (f * 64 + lane) * 8) = o;
  }

  // ---- publish zeros into step-0 buffer (zeros != sentinel) ----
  {
    u64* z = (u64*)(hbuf + (((size_t)mh * 32 + c) * 64 + w * 16) * 16) + lane;
    cstore64(z, 0ull);
  }
  __syncthreads();   // wlds ready

  // ---- hoist W_hh fragments into registers (loop-invariant over t) ----
  bf16x8 wb[3][16];
#pragma unroll
  for (int g = 0; g < 3; ++g)
#pragma unroll
    for (int kt = 0; kt < 16; ++kt)
      wb[g][kt] = *(const bf16x8*)(wlds + ((g * 16 + kt) * 64 + lane) * 8);

  const float b0 = bhh[n0 + lm];
  const float b1 = bhh[H_ + n0 + lm];
  const float b2 = bhh[2 * H_ + n0 + lm];

  const int m0 = mh * 64 + w * 16;
  float hp[4] = {0.f, 0.f, 0.f, 0.f};

  float pir[4], pii[4], pin[4], pfr[4], pfi[4];
  auto prefetch = [&](int t) {
#pragma unroll
    for (int r = 0; r < 4; ++r) {
      size_t mrow = (size_t)(m0 + lq * 4 + r) * T_ + t;
      const float* gip = gi + mrow * (3 * H_) + n0 + lm;
      pir[r] = gip[0];
      pii[r] = gip[H_];
      pin[r] = gip[2 * H_];
      const float* gfp = gf + mrow * (2 * H_) + n0 + lm;
      pfr[r] = gfp[0];
      pfi[r] = gfp[H_];
    }
  };
  prefetch(0);

  // a-frag addressing within a step buffer:
  //   elem = mh*32768 + ct*1024 + (w*16+lm)*16 + colin, ct = kt*2+(lq>>1),
  //   colin = (lq&1)*8
  const size_t habase = (size_t)mh * 32768 + ((size_t)w * 16 + lm) * 16 +
                        (size_t)(lq >> 1) * 1024 + (lq & 1) * 8;

  for (int t = 0; t < T_; ++t) {
    const bf16_t* hstep = hbuf + (size_t)t * 65536;
    union { u64 u[2]; bf16x8 v; } a[16];
    // ---- poll the data itself until no lane sees the NaN sentinel ----
    for (;;) {
      int ok = 1;
#pragma unroll
      for (int kt = 0; kt < 16; ++kt) {
        const u64* ap = (const u64*)(hstep + habase + (size_t)kt * 2048);
        a[kt].u[0] = cload64(ap);
        a[kt].u[1] = cload64(ap + 1);
      }
#pragma unroll
      for (int kt = 0; kt < 16; ++kt)
        ok &= (a[kt].u[0] != SENT) & (a[kt].u[1] != SENT);
      if (__all(ok)) break;
      __builtin_amdgcn_s_sleep(1);
    }

    // ---- MFMA: W in registers, two 8-deep chains per gate ----
    floatx4 acc0[3] = {}, acc1[3] = {};
#pragma unroll
    for (int g = 0; g < 3; ++g)
#pragma unroll
      for (int kt = 0; kt < 16; kt += 2) {
        acc0[g] = __builtin_amdgcn_mfma_f32_16x16x32_bf16(a[kt].v,     wb[g][kt],     acc0[g], 0, 0, 0);
        acc1[g] = __builtin_amdgcn_mfma_f32_16x16x32_bf16(a[kt + 1].v, wb[g][kt + 1], acc1[g], 0, 0, 0);
      }

    // ---- elementwise (no stores yet) ----
    float hy[4];
#pragma unroll
    for (int r = 0; r < 4; ++r) {
      float rg = fsigmoid(pir[r] + acc0[0][r] + acc1[0][r] + b0 + pfr[r]);
      float ig = fsigmoid(pii[r] + acc0[1][r] + acc1[1][r] + b1 + pfi[r]);
      float ng = ftanh(pin[r] + rg * (acc0[2][r] + acc1[2][r] + b2));
      hy[r] = ng + ig * (hp[r] - ng);
      hp[r] = hy[r];
      swp[w][(lq * 4 + r) * 16 + lm] = (bf16_t)hy[r];
    }

    // ---- publish ASAP: wave-internal LDS repack -> one 8B store per lane ----
    if (t + 1 < T_) {
      asm volatile("s_waitcnt lgkmcnt(0)" ::: "memory");
      u64 pk = *(const u64*)(&swp[w][0] + lane * 4);
      u64* dst = (u64*)(hbuf + (size_t)(t + 1) * 65536 +
                        (((size_t)mh * 32 + c) * 64 + w * 16) * 16) + lane;
      cstore64(dst, pk);   // no drain, no flag — consumers poll the data
    }

    // ---- off-critical-path: eo stores, hT, next prefetch ----
#pragma unroll
    for (int r = 0; r < 4; ++r) {
      int brow = m0 + lq * 4 + r;
      size_t mrow = (size_t)brow * T_ + t;
      out[mrow * H_ + n0 + lm] = hy[r];
      if (t == T_ - 1)
        out[(size_t)M_ * H_ + (size_t)brow * H_ + n0 + lm] = hy[r];
    }
    if (t + 1 < T_) prefetch(t + 1);
  }
}

// ---------------------------------------------------------------------------
extern "C" void kernel_launch(void* const* d_in, const int* in_sizes, int n_in,
                              void* d_out, int out_size, void* d_ws, size_t ws_size,
                              hipStream_t stream) {
  const float* feat0 = (const float*)d_in[0];
  const float* feat1 = (const float*)d_in[1];
  const float* W_ih  = (const float*)d_in[2];
  const float* b_ih  = (const float*)d_in[3];
  const float* W_hh  = (const float*)d_in[4];
  const float* b_hh  = (const float*)d_in[5];
  const float* W_fh  = (const float*)d_in[6];
  const float* b_fh  = (const float*)d_in[7];
  float* out = (float*)d_out;

  char* p = (char*)d_ws;
  float*  gi   = (float*)p;  p += (size_t)M_ * 3 * H_ * 4;   // 48 MB
  float*  gf   = (float*)p;  p += (size_t)M_ * 2 * H_ * 4;   // 32 MB
  bf16_t* A1   = (bf16_t*)p; p += (size_t)M_ * IN_ * 2;      // 32 MB
  bf16_t* A0   = (bf16_t*)p; p += (size_t)M_ * FS_ * 2;      // 24 MB
  bf16_t* Wihb = (bf16_t*)p; p += (size_t)3 * H_ * IN_ * 2;  // 6 MB
  bf16_t* Wfhb = (bf16_t*)p; p += (size_t)2 * H_ * FS_ * 2;  // 3 MB

  // h step-buffers alias A0 (dual-GEMM has finished reading A0 by then)
  bf16_t* hbuf = A0;   // 64 steps x 128 KB = 8 MB < 24 MB

  // ---- single fused convert launch (4 regions) ----
  const int e0 = (int)((size_t)M_ * IN_ / 8);                    // feat1 -> A1
  const int e1 = e0 + (int)((size_t)M_ * FS_ / 8);               // feat0 -> A0
  const int e2 = e1 + (int)((size_t)3 * H_ * IN_ / 8);           // W_ih  -> Wihb
  const int e3 = e2 + (int)((size_t)2 * H_ * FS_ / 8);           // W_fh  -> Wfhb
  cvt_all_k<<<(e3 + 255) / 256, 256, 0, stream>>>(
      feat1, A1, e0, feat0, A0, e1, W_ih, Wihb, e2, W_fh, Wfhb, e3);

  // ---- both GEMMs in one launch: 192 + 128 = 320 blocks of 512 threads ----
  gemm_dual<<<320, 512, 0, stream>>>(
      A1, Wihb, b_ih, gi,
      A0, Wfhb, b_fh, gf);

  // sentinel-fill the h step-buffers (after dual-GEMM consumed A0)
  hipMemsetAsync(hbuf, 0xFF, (size_t)T_ * 65536 * sizeof(bf16_t), stream);

  gru_scan<<<GB_, 256, 0, stream>>>(W_hh, b_hh, gi, gf, hbuf, out);
}

// Round 8
// 475.577 us; speedup vs baseline: 2.4197x; 1.0366x over previous
//
#include <hip/hip_runtime.h>
#include <cstdint>
#include <cstddef>

typedef __bf16 bf16_t;
typedef bf16_t bf16x8 __attribute__((ext_vector_type(8)));
typedef float floatx4 __attribute__((ext_vector_type(4)));
typedef unsigned long long u64;

#define B_   128
#define T_   64
#define H_   512
#define IN_  2048
#define FS_  1536
#define M_   (B_ * T_)   // 8192
#define GB_  64
#define SENT (~0ull)     // 0xFF... = 4x bf16 NaN — GRU outputs can never be NaN

// ---------------------------------------------------------------------------
__device__ __forceinline__ void async16(void* lds, const void* gp) {
  __builtin_amdgcn_global_load_lds(
      (const __attribute__((address_space(1))) void*)gp,
      (__attribute__((address_space(3))) void*)lds, 16, 0, 0);
}

// Coherent (agent-scope relaxed) ops — served at the MALL coherence point.
__device__ __forceinline__ u64 cload64(const u64* p) {
  return __hip_atomic_load((u64*)p, __ATOMIC_RELAXED, __HIP_MEMORY_SCOPE_AGENT);
}
__device__ __forceinline__ void cstore64(u64* p, u64 v) {
  __hip_atomic_store(p, v, __ATOMIC_RELAXED, __HIP_MEMORY_SCOPE_AGENT);
}

__device__ __forceinline__ float fsigmoid(float x) {
  return __builtin_amdgcn_rcpf(1.f + __expf(-x));
}
__device__ __forceinline__ float ftanh(float x) {
  return 2.f * __builtin_amdgcn_rcpf(1.f + __expf(-2.f * x)) - 1.f;
}

// ---------------------------------------------------------------------------
// Fused fp32->bf16 convert for all four tensors in ONE launch.
// ---------------------------------------------------------------------------
__global__ __launch_bounds__(256) void cvt_all_k(
    const float* __restrict__ s0, bf16_t* __restrict__ d0, int e0,
    const float* __restrict__ s1, bf16_t* __restrict__ d1, int e1,
    const float* __restrict__ s2, bf16_t* __restrict__ d2, int e2,
    const float* __restrict__ s3, bf16_t* __restrict__ d3, int e3) {
  int i = blockIdx.x * 256 + threadIdx.x;
  if (i >= e3) return;
  const float* s; bf16_t* d; int base;
  if (i < e1) {
    if (i < e0) { s = s0; d = d0; base = 0;  }
    else        { s = s1; d = d1; base = e0; }
  } else {
    if (i < e2) { s = s2; d = d2; base = e1; }
    else        { s = s3; d = d3; base = e2; }
  }
  size_t j = (size_t)(i - base);
  const float4* s4 = (const float4*)s;
  float4 v0 = s4[2 * j];
  float4 v1 = s4[2 * j + 1];
  bf16x8 o;
  o[0] = (bf16_t)v0.x; o[1] = (bf16_t)v0.y; o[2] = (bf16_t)v0.z; o[3] = (bf16_t)v0.w;
  o[4] = (bf16_t)v1.x; o[5] = (bf16_t)v1.y; o[6] = (bf16_t)v1.z; o[7] = (bf16_t)v1.w;
  *(bf16x8*)(d + j * 8) = o;
}

// ---------------------------------------------------------------------------
// DUAL GEMM, 128x128 tile — REVERTED to the round-5 verified best config.
// Round 6/7 lesson (matches guide m105/m112): 256^2 tiles LOSE at the simple
// 2-barrier structure (1 block/CU kills cross-block TLP that hides the
// barrier stalls); 256^2 only pays with the deep 8-phase schedule.
//   p <  768: GEMM1 tile  (A1 x Wihb^T -> gi, 12x64 tiles)
//   p >= 768: GEMM2 tile  (A0 x Wfhb^T -> gf,  8x64 tiles)
// Per-range bijective XCD swizzle. Counted-vmcnt 2-deep pipeline:
//   prologue stage t0->buf0, t1->buf1; per iter vmcnt(4) [own tile landed,
//   next in flight] -> s_barrier -> ds_read+MFMA -> s_barrier -> restage
//   buf[cur] for t+2. Last iter vmcnt(0).
// ---------------------------------------------------------------------------
#define BM 128
#define BN 128
#define BK 32

__global__ __launch_bounds__(256) void gemm_dual(
    const bf16_t* __restrict__ A1g, const bf16_t* __restrict__ W1g,
    const float* __restrict__ bias1, float* __restrict__ C1g,
    const bf16_t* __restrict__ A2g, const bf16_t* __restrict__ W2g,
    const float* __restrict__ bias2, float* __restrict__ C2g) {
  __shared__ __align__(16) bf16_t As[2][BM * BK];
  __shared__ __align__(16) bf16_t Bs[2][BN * BK];

  const int tid  = threadIdx.x;
  const int lane = tid & 63;
  const int wave = tid >> 6;
  const int wr = wave >> 1, wc = wave & 1;

  // ---- sub-kernel select + per-range XCD swizzle (block-uniform) ----
  const bf16_t *A, *Bm; const float* bias; float* C;
  int N, K, id, gx;
  const int p = blockIdx.x;
  if (p < 768) {
    A = A1g; Bm = W1g; bias = bias1; C = C1g;
    N = 3 * H_; K = IN_;
    id = (p & 7) * 96 + (p >> 3);   // nwg=768, chunk=96
    gx = 12;                        // N/BN
  } else {
    const int q = p - 768;
    A = A2g; Bm = W2g; bias = bias2; C = C2g;
    N = 2 * H_; K = FS_;
    id = (q & 7) * 64 + (q >> 3);   // nwg=512, chunk=64
    gx = 8;
  }
  const int bx = id % gx;
  const int by = id / gx;
  const int mblk = by * BM;
  const int nblk = bx * BN;

  const int sr = lane >> 2;
  const int sc = (lane & 3) * 8;
  const int c0 = wave * 2;
  const int so = c0 * 512;

  const bf16_t* Ag0 = A + (size_t)(mblk + c0 * 16 + sr) * K + sc;
  const bf16_t* Ag1 = A + (size_t)(mblk + c0 * 16 + 16 + sr) * K + sc;
  const bf16_t* Bg0 = Bm + (size_t)(nblk + c0 * 16 + sr) * K + sc;
  const bf16_t* Bg1 = Bm + (size_t)(nblk + c0 * 16 + 16 + sr) * K + sc;

  floatx4 acc[4][4] = {};

  const int fm = lane & 15;
  const int fk = (lane >> 4) * 8;

  auto stage = [&](int buf, int kt) {
    async16(As[buf] + so,       Ag0 + kt);
    async16(As[buf] + so + 512, Ag1 + kt);
    async16(Bs[buf] + so,       Bg0 + kt);
    async16(Bs[buf] + so + 512, Bg1 + kt);
  };

  // ---- prologue: 2 tiles in flight ----
  stage(0, 0);
  stage(1, BK);

  int cur = 0;
  for (int kt = 0; kt < K; kt += BK) {
    if (kt + BK < K)
      asm volatile("s_waitcnt vmcnt(4)" ::: "memory");
    else
      asm volatile("s_waitcnt vmcnt(0)" ::: "memory");
    asm volatile("s_barrier" ::: "memory");   // all waves' tile-kt writes landed

    bf16x8 a[4], b[4];
#pragma unroll
    for (int i = 0; i < 4; i++)
      a[i] = *(const bf16x8*)(As[cur] + (wr * 64 + i * 16 + fm) * BK + fk);
#pragma unroll
    for (int j = 0; j < 4; j++)
      b[j] = *(const bf16x8*)(Bs[cur] + (wc * 64 + j * 16 + fm) * BK + fk);
#pragma unroll
    for (int i = 0; i < 4; i++)
#pragma unroll
      for (int j = 0; j < 4; j++)
        acc[i][j] = __builtin_amdgcn_mfma_f32_16x16x32_bf16(a[i], b[j], acc[i][j], 0, 0, 0);

    asm volatile("s_barrier" ::: "memory");   // all waves done reading buf[cur]
    if (kt + 2 * BK < K) stage(cur, kt + 2 * BK);   // refill for tile kt+2
    cur ^= 1;
  }

  const int en  = nblk + wc * 64 + (lane & 15);
  const int em0 = mblk + wr * 64 + (lane >> 4) * 4;
#pragma unroll
  for (int j = 0; j < 4; j++) {
    int col = en + j * 16;
    float bv = bias[col];
#pragma unroll
    for (int i = 0; i < 4; i++) {
#pragma unroll
      for (int r = 0; r < 4; r++) {
        int row = em0 + i * 16 + r;
        C[(size_t)row * N + col] = acc[i][j][r] + bv;
      }
    }
  }
}

// ---------------------------------------------------------------------------
// Persistent GRU scan — FLAGLESS producer/consumer.
// Identical to the round-2..7 PASSING version EXCEPT one deliberate,
// dataflow-preserving change: the poll loop's s_sleep(1) backoff is removed
// (same loads, same per-word sentinel validation, same __all gate — only the
// retry cadence tightens, cutting poll-overshoot ~300 cy/step). The gating
// STRUCTURE stays frozen (round-1 lesson: never change which words gate).
// ---------------------------------------------------------------------------
__global__ __launch_bounds__(256, 1) void gru_scan(
    const float* __restrict__ Whh_f,  // [3H][H] fp32
    const float* __restrict__ bhh,
    const float* __restrict__ gi,     // [M][3H]
    const float* __restrict__ gf,     // [M][2H]
    bf16_t* __restrict__ hbuf,        // 64 x 65536 elems (8 MB), 0xFF-init
    float* __restrict__ out) {        // eo [B*T][H] ++ hT [B][H]
  __shared__ __align__(16) bf16_t wlds[48 * 64 * 8];  // 48 KB (init staging only)
  __shared__ __align__(16) bf16_t swp[4][256];        // repack scratch

  const int tid  = threadIdx.x;
  const int lane = tid & 63;
  const int w    = tid >> 6;
  const int lm   = lane & 15;
  const int lq   = lane >> 4;
  const int c    = blockIdx.x >> 1;
  const int mh   = blockIdx.x & 1;
  const int n0   = c * 16;

  // ---- W_hh slice -> LDS (fragment order), once ----
  for (int f = w; f < 48; f += 4) {
    int g = f >> 4, kt = f & 15;
    const float* src = Whh_f + (size_t)(g * H_ + n0 + lm) * H_ + kt * 32 + lq * 8;
    float4 v0 = *(const float4*)src;
    float4 v1 = *(const float4*)(src + 4);
    bf16x8 o;
    o[0] = (bf16_t)v0.x; o[1] = (bf16_t)v0.y; o[2] = (bf16_t)v0.z; o[3] = (bf16_t)v0.w;
    o[4] = (bf16_t)v1.x; o[5] = (bf16_t)v1.y; o[6] = (bf16_t)v1.z; o[7] = (bf16_t)v1.w;
    *(bf16x8*)(wlds + (f * 64 + lane) * 8) = o;
  }

  // ---- publish zeros into step-0 buffer (zeros != sentinel) ----
  {
    u64* z = (u64*)(hbuf + (((size_t)mh * 32 + c) * 64 + w * 16) * 16) + lane;
    cstore64(z, 0ull);
  }
  __syncthreads();   // wlds ready

  // ---- hoist W_hh fragments into registers (loop-invariant over t) ----
  bf16x8 wb[3][16];
#pragma unroll
  for (int g = 0; g < 3; ++g)
#pragma unroll
    for (int kt = 0; kt < 16; ++kt)
      wb[g][kt] = *(const bf16x8*)(wlds + ((g * 16 + kt) * 64 + lane) * 8);

  const float b0 = bhh[n0 + lm];
  const float b1 = bhh[H_ + n0 + lm];
  const float b2 = bhh[2 * H_ + n0 + lm];

  const int m0 = mh * 64 + w * 16;
  float hp[4] = {0.f, 0.f, 0.f, 0.f};

  float pir[4], pii[4], pin[4], pfr[4], pfi[4];
  auto prefetch = [&](int t) {
#pragma unroll
    for (int r = 0; r < 4; ++r) {
      size_t mrow = (size_t)(m0 + lq * 4 + r) * T_ + t;
      const float* gip = gi + mrow * (3 * H_) + n0 + lm;
      pir[r] = gip[0];
      pii[r] = gip[H_];
      pin[r] = gip[2 * H_];
      const float* gfp = gf + mrow * (2 * H_) + n0 + lm;
      pfr[r] = gfp[0];
      pfi[r] = gfp[H_];
    }
  };
  prefetch(0);

  // a-frag addressing within a step buffer:
  //   elem = mh*32768 + ct*1024 + (w*16+lm)*16 + colin, ct = kt*2+(lq>>1),
  //   colin = (lq&1)*8
  const size_t habase = (size_t)mh * 32768 + ((size_t)w * 16 + lm) * 16 +
                        (size_t)(lq >> 1) * 1024 + (lq & 1) * 8;

  for (int t = 0; t < T_; ++t) {
    const bf16_t* hstep = hbuf + (size_t)t * 65536;
    union { u64 u[2]; bf16x8 v; } a[16];
    // ---- poll the data itself until no lane sees the NaN sentinel ----
    for (;;) {
      int ok = 1;
#pragma unroll
      for (int kt = 0; kt < 16; ++kt) {
        const u64* ap = (const u64*)(hstep + habase + (size_t)kt * 2048);
        a[kt].u[0] = cload64(ap);
        a[kt].u[1] = cload64(ap + 1);
      }
#pragma unroll
      for (int kt = 0; kt < 16; ++kt)
        ok &= (a[kt].u[0] != SENT) & (a[kt].u[1] != SENT);
      if (__all(ok)) break;
    }

    // ---- MFMA: W in registers, two 8-deep chains per gate ----
    floatx4 acc0[3] = {}, acc1[3] = {};
#pragma unroll
    for (int g = 0; g < 3; ++g)
#pragma unroll
      for (int kt = 0; kt < 16; kt += 2) {
        acc0[g] = __builtin_amdgcn_mfma_f32_16x16x32_bf16(a[kt].v,     wb[g][kt],     acc0[g], 0, 0, 0);
        acc1[g] = __builtin_amdgcn_mfma_f32_16x16x32_bf16(a[kt + 1].v, wb[g][kt + 1], acc1[g], 0, 0, 0);
      }

    // ---- elementwise (no stores yet) ----
    float hy[4];
#pragma unroll
    for (int r = 0; r < 4; ++r) {
      float rg = fsigmoid(pir[r] + acc0[0][r] + acc1[0][r] + b0 + pfr[r]);
      float ig = fsigmoid(pii[r] + acc0[1][r] + acc1[1][r] + b1 + pfi[r]);
      float ng = ftanh(pin[r] + rg * (acc0[2][r] + acc1[2][r] + b2));
      hy[r] = ng + ig * (hp[r] - ng);
      hp[r] = hy[r];
      swp[w][(lq * 4 + r) * 16 + lm] = (bf16_t)hy[r];
    }

    // ---- publish ASAP: wave-internal LDS repack -> one 8B store per lane ----
    if (t + 1 < T_) {
      asm volatile("s_waitcnt lgkmcnt(0)" ::: "memory");
      u64 pk = *(const u64*)(&swp[w][0] + lane * 4);
      u64* dst = (u64*)(hbuf + (size_t)(t + 1) * 65536 +
                        (((size_t)mh * 32 + c) * 64 + w * 16) * 16) + lane;
      cstore64(dst, pk);   // no drain, no flag — consumers poll the data
    }

    // ---- off-critical-path: eo stores, hT, next prefetch ----
#pragma unroll
    for (int r = 0; r < 4; ++r) {
      int brow = m0 + lq * 4 + r;
      size_t mrow = (size_t)brow * T_ + t;
      out[mrow * H_ + n0 + lm] = hy[r];
      if (t == T_ - 1)
        out[(size_t)M_ * H_ + (size_t)brow * H_ + n0 + lm] = hy[r];
    }
    if (t + 1 < T_) prefetch(t + 1);
  }
}

// ---------------------------------------------------------------------------
extern "C" void kernel_launch(void* const* d_in, const int* in_sizes, int n_in,
                              void* d_out, int out_size, void* d_ws, size_t ws_size,
                              hipStream_t stream) {
  const float* feat0 = (const float*)d_in[0];
  const float* feat1 = (const float*)d_in[1];
  const float* W_ih  = (const float*)d_in[2];
  const float* b_ih  = (const float*)d_in[3];
  const float* W_hh  = (const float*)d_in[4];
  const float* b_hh  = (const float*)d_in[5];
  const float* W_fh  = (const float*)d_in[6];
  const float* b_fh  = (const float*)d_in[7];
  float* out = (float*)d_out;

  char* p = (char*)d_ws;
  float*  gi   = (float*)p;  p += (size_t)M_ * 3 * H_ * 4;   // 48 MB
  float*  gf   = (float*)p;  p += (size_t)M_ * 2 * H_ * 4;   // 32 MB
  bf16_t* A1   = (bf16_t*)p; p += (size_t)M_ * IN_ * 2;      // 32 MB
  bf16_t* A0   = (bf16_t*)p; p += (size_t)M_ * FS_ * 2;      // 24 MB
  bf16_t* Wihb = (bf16_t*)p; p += (size_t)3 * H_ * IN_ * 2;  // 6 MB
  bf16_t* Wfhb = (bf16_t*)p; p += (size_t)2 * H_ * FS_ * 2;  // 3 MB

  // h step-buffers alias A0 (dual-GEMM has finished reading A0 by then)
  bf16_t* hbuf = A0;   // 64 steps x 128 KB = 8 MB < 24 MB

  // ---- single fused convert launch (4 regions) ----
  const int e0 = (int)((size_t)M_ * IN_ / 8);                    // feat1 -> A1
  const int e1 = e0 + (int)((size_t)M_ * FS_ / 8);               // feat0 -> A0
  const int e2 = e1 + (int)((size_t)3 * H_ * IN_ / 8);           // W_ih  -> Wihb
  const int e3 = e2 + (int)((size_t)2 * H_ * FS_ / 8);           // W_fh  -> Wfhb
  cvt_all_k<<<(e3 + 255) / 256, 256, 0, stream>>>(
      feat1, A1, e0, feat0, A0, e1, W_ih, Wihb, e2, W_fh, Wfhb, e3);

  // ---- both GEMMs in one launch: 768 + 512 = 1280 blocks of 256 threads ----
  gemm_dual<<<1280, 256, 0, stream>>>(
      A1, Wihb, b_ih, gi,
      A0, Wfhb, b_fh, gf);

  // sentinel-fill the h step-buffers (after dual-GEMM consumed A0)
  hipMemsetAsync(hbuf, 0xFF, (size_t)T_ * 65536 * sizeof(bf16_t), stream);

  gru_scan<<<GB_, 256, 0, stream>>>(W_hh, b_hh, gi, gf, hbuf, out);
}